// Round 7
// baseline (686.857 us; speedup 1.0000x reference)
//
#include <hip/hip_runtime.h>
#include <math.h>

#define NDIM 4096
#define CDIM 256
#define KD   32
#define SCALE 0.17677669529663687f  // 1/sqrt(32)
#define SHIFT 8.0f

typedef __attribute__((ext_vector_type(8))) short short8;  // 8 bf16 = 4 VGPRs
typedef __attribute__((ext_vector_type(4))) float f32x4;
typedef unsigned short u16;
typedef unsigned int u32;

__device__ __forceinline__ u32 f2bf(float x) {  // fp32 -> bf16 bits, RNE
  union { float f; u32 u; } v; v.f = x;
  return (v.u + 0x7FFFu + ((v.u >> 16) & 1u)) >> 16;
}

#define MFMA16(a, b, c) __builtin_amdgcn_mfma_f32_16x16x32_bf16((a), (b), (c), 0, 0, 0)

// ---------------------------------------------------------------------------
// cast all weights fp32 -> bf16 into one contiguous ws region
// ---------------------------------------------------------------------------
__global__ void cast_all_kernel(const float* __restrict__ h1w,
                                const float* __restrict__ h2w,
                                const float* __restrict__ fw,
                                const float* __restrict__ gw,
                                u16* __restrict__ dst) {
  int i = blockIdx.x * 256 + threadIdx.x;
  float v;
  if (i < 65536) v = h1w[i];
  else if (i < 131072) v = h2w[i - 65536];
  else if (i < 139264) v = fw[i - 131072];
  else v = gw[i - 139264];
  dst[i] = (u16)f2bf(v);
}

// ---------------------------------------------------------------------------
// x[b][C][n] fp32 -> xT[bb][n][C] bf16
// ---------------------------------------------------------------------------
__global__ __launch_bounds__(256) void transpose_cast_kernel(
    const float* __restrict__ x1, const float* __restrict__ x2,
    u16* __restrict__ xt) {
  __shared__ float ts[64][68];
  const int t = threadIdx.x;
  const int ntile = blockIdx.x * 64, Ctile = blockIdx.y * 64, z = blockIdx.z;
  const float* xb = ((z >> 2) ? x2 : x1) + (size_t)(z & 3) * CDIM * NDIM;
  u16* xtb = xt + (size_t)z * NDIM * CDIM;
  const int r = t >> 4, c4 = (t & 15) * 4;
#pragma unroll
  for (int i = 0; i < 4; i++) {
    float4 v = *(const float4*)&xb[(size_t)(Ctile + r + i * 16) * NDIM + ntile + c4];
    *(float4*)&ts[r + i * 16][c4] = v;
  }
  __syncthreads();
  const int n = t >> 2, Cg = (t & 3) * 16;
  u32 pk[8];
#pragma unroll
  for (int j = 0; j < 8; j++) {
    u32 lo = f2bf(ts[Cg + 2 * j][n]);
    u32 hi = f2bf(ts[Cg + 2 * j + 1][n]);
    pk[j] = lo | (hi << 16);
  }
  uint4* dst = (uint4*)&xtb[(size_t)(ntile + n) * CDIM + Ctile + Cg];
  dst[0] = make_uint4(pk[0], pk[1], pk[2], pk[3]);
  dst[1] = make_uint4(pk[4], pk[5], pk[6], pk[7]);
}

// ---------------------------------------------------------------------------
// conv f+g fused via MFMA. block 256 (4 waves), tile 32o x 64n, grid (64, 8)
// ---------------------------------------------------------------------------
__global__ __launch_bounds__(256) void conv_fg_kernel(
    const u16* __restrict__ Wf, const float* __restrict__ fbias,
    const u16* __restrict__ Wg, const float* __restrict__ gbias,
    const u16* __restrict__ xt, u16* __restrict__ ftT, u16* __restrict__ gtT) {
  const int t = threadIdx.x, w = t >> 6, l = t & 63, li = l & 15, q = l >> 4;
  const int ntile = blockIdx.x * 64, bb = blockIdx.y;
  const u16* xtb = xt + (size_t)bb * NDIM * CDIM;
  f32x4 zero4 = {0.f, 0.f, 0.f, 0.f};
  f32x4 acc[2][2];
  for (int i = 0; i < 2; i++) for (int j = 0; j < 2; j++) acc[i][j] = zero4;
  const int nrow = ntile + w * 16 + li;

  for (int k0 = 0; k0 < CDIM; k0 += 32) {
    short8 bx = *(const short8*)&xtb[(size_t)nrow * CDIM + k0 + q * 8];
    short8 af0 = *(const short8*)&Wf[(size_t)(li) * CDIM + k0 + q * 8];
    short8 af1 = *(const short8*)&Wf[(size_t)(16 + li) * CDIM + k0 + q * 8];
    short8 ag0 = *(const short8*)&Wg[(size_t)(li) * CDIM + k0 + q * 8];
    short8 ag1 = *(const short8*)&Wg[(size_t)(16 + li) * CDIM + k0 + q * 8];
    acc[0][0] = MFMA16(af0, bx, acc[0][0]);
    acc[0][1] = MFMA16(af1, bx, acc[0][1]);
    acc[1][0] = MFMA16(ag0, bx, acc[1][0]);
    acc[1][1] = MFMA16(ag1, bx, acc[1][1]);
  }
  u16* outs[2] = {ftT + (size_t)bb * NDIM * KD, gtT + (size_t)bb * NDIM * KD};
  const float* biases[2] = {fbias, gbias};
#pragma unroll
  for (int fg = 0; fg < 2; fg++) {
#pragma unroll
    for (int os = 0; os < 2; os++) {
      float b0 = biases[fg][os * 16 + q * 4 + 0];
      float b1 = biases[fg][os * 16 + q * 4 + 1];
      float b2 = biases[fg][os * 16 + q * 4 + 2];
      float b3 = biases[fg][os * 16 + q * 4 + 3];
      u32 p0 = f2bf(acc[fg][os][0] + b0) | (f2bf(acc[fg][os][1] + b1) << 16);
      u32 p1 = f2bf(acc[fg][os][2] + b2) | (f2bf(acc[fg][os][3] + b3) << 16);
      *(uint2*)&outs[fg][(size_t)nrow * KD + os * 16 + q * 4] = make_uint2(p0, p1);
    }
  }
}

// ---------------------------------------------------------------------------
// stats: L[n] = SHIFT + log(sum_m exp(s[n,m]-SHIFT))
// ---------------------------------------------------------------------------
__global__ __launch_bounds__(256) void stats_kernel(
    const u16* __restrict__ ft, const u16* __restrict__ gt,
    float* __restrict__ L) {
  __shared__ float zred[32][64];
  const int t = threadIdx.x, w = t >> 6, l = t & 63, li = l & 15, q = l >> 4;
  const int n0 = blockIdx.x * 32;
  const int bb = blockIdx.z * 4 + blockIdx.y;
  const u16* ftb = ft + (size_t)bb * NDIM * KD;
  const u16* gtb = gt + (size_t)bb * NDIM * KD;
  f32x4 zero4 = {0.f, 0.f, 0.f, 0.f};

  short8 a0 = *(const short8*)&ftb[(size_t)(n0 + li) * KD + q * 8];
  short8 a1 = *(const short8*)&ftb[(size_t)(n0 + 16 + li) * KD + q * 8];
  f32x4 z0 = zero4, z1 = zero4;

#pragma unroll 2
  for (int it = 0; it < 64; it++) {
    int m = (it * 4 + w) * 16;
    short8 bf = *(const short8*)&gtb[(size_t)(m + li) * KD + q * 8];
    f32x4 S0 = MFMA16(a0, bf, zero4);
    f32x4 S1 = MFMA16(a1, bf, zero4);
#pragma unroll
    for (int reg = 0; reg < 4; reg++) {
      z0[reg] += __expf(S0[reg] * SCALE - SHIFT);
      z1[reg] += __expf(S1[reg] * SCALE - SHIFT);
    }
  }
#pragma unroll
  for (int reg = 0; reg < 4; reg++) {
    zred[q * 4 + reg][w * 16 + li] = z0[reg];
    zred[16 + q * 4 + reg][w * 16 + li] = z1[reg];
  }
  __syncthreads();
  const int r = t >> 3, i8 = t & 7;
  float4 s1 = *(const float4*)&zred[r][i8 * 8];
  float4 s2 = *(const float4*)&zred[r][i8 * 8 + 4];
  float sum = s1.x + s1.y + s1.z + s1.w + s2.x + s2.y + s2.z + s2.w;
  sum += __shfl_xor(sum, 1, 8);
  sum += __shfl_xor(sum, 2, 8);
  sum += __shfl_xor(sum, 4, 8);
  if (i8 == 0) L[(size_t)bb * NDIM + n0 + r] = SHIFT + __logf(sum);
}

// ---------------------------------------------------------------------------
// conv h (both branches) via MFMA, with e^{-L[n]} folded into the output:
// h'[c][n] = (W @ x + bias)[c][n] * exp(-L[n]).
// ---------------------------------------------------------------------------
__global__ __launch_bounds__(256) void conv_h_kernel(
    const u16* __restrict__ Wall, const float* __restrict__ b1,
    const float* __restrict__ b2, const u16* __restrict__ xt,
    const float* __restrict__ L, u16* __restrict__ outH) {
  const int t = threadIdx.x, w = t >> 6, l = t & 63, li = l & 15, q = l >> 4;
  const int ntile = blockIdx.x * 64;
  const int o0 = blockIdx.y * 64 + w * 16;
  const int bb = blockIdx.z, branch = bb >> 2;
  const u16* W = Wall + (size_t)branch * CDIM * CDIM;
  const float* bias = branch ? b2 : b1;
  const u16* xtb = xt + (size_t)bb * NDIM * CDIM;
  const float* Lb = L + (size_t)bb * NDIM;
  u16* ob = outH + (size_t)bb * CDIM * NDIM;
  f32x4 zero4 = {0.f, 0.f, 0.f, 0.f};
  f32x4 acc[4];
  for (int i = 0; i < 4; i++) acc[i] = zero4;

  for (int k0 = 0; k0 < CDIM; k0 += 32) {
    short8 a = *(const short8*)&W[(size_t)(o0 + li) * CDIM + k0 + q * 8];
#pragma unroll
    for (int ns = 0; ns < 4; ns++) {
      short8 bf = *(const short8*)&xtb[(size_t)(ntile + ns * 16 + li) * CDIM + k0 + q * 8];
      acc[ns] = MFMA16(a, bf, acc[ns]);
    }
  }
  float bv[4];
#pragma unroll
  for (int reg = 0; reg < 4; reg++) bv[reg] = bias[o0 + q * 4 + reg];
#pragma unroll
  for (int ns = 0; ns < 4; ns++) {
    int n = ntile + ns * 16 + li;
    float ex = __expf(-Lb[n]);
#pragma unroll
    for (int reg = 0; reg < 4; reg++) {
      int c = o0 + q * 4 + reg;
      ob[(size_t)c * NDIM + n] = (u16)f2bf((acc[ns][reg] + bv[reg]) * ex);
    }
  }
}

// ---------------------------------------------------------------------------
// apply v7 (barrier-free): out[c][m] = gamma*sum_n h'[c,n]*exp(s[n,m]*SCALE)+x
// Each wave independently owns 128c x 16m. Per 64-n chunk:
//   4 score MFMAs (its own m-column of P), exp, pack;
//   C->B layout transform IN REGISTERS via __shfl (8 shfl + 4 sel per B-frag);
//   16 PV MFMAs. NO __syncthreads, NO LDS.
// Block 512 = 8 waves: w&1 = c-half, w>>1 = m-subtile. grid (64, 4, 2).
// Score work duplicated x2 over c-halves (total MFMA 86 GF, floor ~41 us).
// ---------------------------------------------------------------------------
__global__ __launch_bounds__(512, 4) void apply_kernel(
    const u16* __restrict__ ft, const u16* __restrict__ gt,
    const u16* __restrict__ h,
    const float* __restrict__ x1, const float* __restrict__ x2,
    const float* __restrict__ gamma1, const float* __restrict__ gamma2,
    float* __restrict__ out) {
  const int t = threadIdx.x, w = t >> 6, l = t & 63, li = l & 15, q = l >> 4;
  const int mtile = blockIdx.x * 64;
  const int b = blockIdx.y, br = blockIdx.z, bb = br * 4 + b;
  const int c0 = (w & 1) * 128;
  const int m0 = mtile + (w >> 1) * 16;
  const u16* ftb = ft + (size_t)bb * NDIM * KD;
  const u16* gtb = gt + (size_t)bb * NDIM * KD;
  const u16* hb = h + (size_t)bb * CDIM * NDIM;
  const float* xb = (br ? x2 : x1) + (size_t)b * CDIM * NDIM;
  const float gmv = br ? gamma2[0] : gamma1[0];
  float* ob = out + (size_t)bb * CDIM * NDIM;

  f32x4 zero4 = {0.f, 0.f, 0.f, 0.f};
  short8 gfrag = *(const short8*)&gtb[(size_t)(m0 + li) * KD + q * 8];

  f32x4 acc[8];
#pragma unroll
  for (int i = 0; i < 8; i++) acc[i] = zero4;

  // shuffle source lanes for the C->B transform (see derivation in journal):
  // B-frag dword j' <- dword (j'&1) of lane ((q&1)*2+(j'>>1))*16+li of tile
  // 2kh+(q>>1).
  const int lane_lo = ((q & 1) * 2) * 16 + li;  // j'=0,1
  const int lane_hi = lane_lo + 16;             // j'=2,3
  const bool qlow = (q < 2);                    // tile 2kh vs 2kh+1

  short8 afA[4];
#pragma unroll
  for (int ns = 0; ns < 4; ns++)
    afA[ns] = *(const short8*)&ftb[(size_t)(ns * 16 + li) * KD + q * 8];

  for (int i = 0; i < 64; i++) {
    const int n0 = i * 64;
    // h A-frags kh=0 issued first: latency hides behind score+exp+shfl
    short8 ah0[8];
#pragma unroll
    for (int cs = 0; cs < 8; cs++)
      ah0[cs] = *(const short8*)&hb[(size_t)(c0 + cs * 16 + li) * NDIM + n0 + q * 8];

    // 4 score tiles for this wave's 16 m: S[n=ns*16+q*4+reg][m=li]
    u32 Td0[4], Td1[4];
#pragma unroll
    for (int ns = 0; ns < 4; ns++) {
      f32x4 S = MFMA16(afA[ns], gfrag, zero4);
      float p0 = __expf(S[0] * SCALE), p1 = __expf(S[1] * SCALE);
      float p2 = __expf(S[2] * SCALE), p3 = __expf(S[3] * SCALE);
      Td0[ns] = f2bf(p0) | (f2bf(p1) << 16);   // n-pair (q*4+0, q*4+1)
      Td1[ns] = f2bf(p2) | (f2bf(p3) << 16);   // n-pair (q*4+2, q*4+3)
    }

    // prefetch f for next chunk (last iter: dummy re-read of chunk 0)
    {
      const int nn = (i + 1 < 64) ? (i + 1) * 64 : 0;
#pragma unroll
      for (int ns = 0; ns < 4; ns++)
        afA[ns] = *(const short8*)&ftb[(size_t)(nn + ns * 16 + li) * KD + q * 8];
    }

    // B-frags via cross-lane permute (no LDS, no barrier)
    union { u32 d[4]; short8 s; } bm0, bm1;
    {
      u32 a0 = __shfl(Td0[0], lane_lo), a1 = __shfl(Td1[0], lane_lo);
      u32 a2 = __shfl(Td0[0], lane_hi), a3 = __shfl(Td1[0], lane_hi);
      u32 b0 = __shfl(Td0[1], lane_lo), b1 = __shfl(Td1[1], lane_lo);
      u32 b2 = __shfl(Td0[1], lane_hi), b3 = __shfl(Td1[1], lane_hi);
      bm0.d[0] = qlow ? a0 : b0; bm0.d[1] = qlow ? a1 : b1;
      bm0.d[2] = qlow ? a2 : b2; bm0.d[3] = qlow ? a3 : b3;
    }
    {
      u32 a0 = __shfl(Td0[2], lane_lo), a1 = __shfl(Td1[2], lane_lo);
      u32 a2 = __shfl(Td0[2], lane_hi), a3 = __shfl(Td1[2], lane_hi);
      u32 b0 = __shfl(Td0[3], lane_lo), b1 = __shfl(Td1[3], lane_lo);
      u32 b2 = __shfl(Td0[3], lane_hi), b3 = __shfl(Td1[3], lane_hi);
      bm1.d[0] = qlow ? a0 : b0; bm1.d[1] = qlow ? a1 : b1;
      bm1.d[2] = qlow ? a2 : b2; bm1.d[3] = qlow ? a3 : b3;
    }

    // h A-frags kh=1 (latency hides behind PV kh=0)
    short8 ah1[8];
#pragma unroll
    for (int cs = 0; cs < 8; cs++)
      ah1[cs] = *(const short8*)&hb[(size_t)(c0 + cs * 16 + li) * NDIM + n0 + 32 + q * 8];

    // PV: 16 MFMAs
#pragma unroll
    for (int cs = 0; cs < 8; cs++) acc[cs] = MFMA16(ah0[cs], bm0.s, acc[cs]);
#pragma unroll
    for (int cs = 0; cs < 8; cs++) acc[cs] = MFMA16(ah1[cs], bm1.s, acc[cs]);
  }

  // epilogue: out = gamma * acc + x   (D-layout: row c=q*4+reg, col m=li)
#pragma unroll
  for (int cs = 0; cs < 8; cs++) {
#pragma unroll
    for (int reg = 0; reg < 4; reg++) {
      int c = c0 + cs * 16 + q * 4 + reg;
      size_t idx = (size_t)c * NDIM + m0 + li;
      ob[idx] = gmv * acc[cs][reg] + xb[idx];
    }
  }
}

// ---------------------------------------------------------------------------
extern "C" void kernel_launch(void* const* d_in, const int* in_sizes, int n_in,
                              void* d_out, int out_size, void* d_ws, size_t ws_size,
                              hipStream_t stream) {
  const float* x1 = (const float*)d_in[0];
  const float* x2 = (const float*)d_in[1];
  const float* f_w = (const float*)d_in[2];
  const float* f_b = (const float*)d_in[3];
  const float* g_w = (const float*)d_in[4];
  const float* g_b = (const float*)d_in[5];
  const float* h1_w = (const float*)d_in[6];
  const float* h1_b = (const float*)d_in[7];
  const float* h2_w = (const float*)d_in[8];
  const float* h2_b = (const float*)d_in[9];
  const float* gamma1 = (const float*)d_in[10];
  const float* gamma2 = (const float*)d_in[11];
  float* out = (float*)d_out;

  char* ws = (char*)d_ws;
  u16* xt  = (u16*)(ws);                          // [8][4096][256]  16 MB
  u16* wh  = (u16*)(ws + 16777216);               // [8][256][4096]  16 MB
  u16* ftw = (u16*)(ws + 33554432);               // [8][4096][32]    2 MB
  u16* gtw = (u16*)(ws + 35651584);               // [8][4096][32]    2 MB
  u16* wWh = (u16*)(ws + 37748736);               // [2][256][256]  256 KB
  u16* wWf = (u16*)(ws + 38010880);               // [32][256]       16 KB
  u16* wWg = (u16*)(ws + 38027264);               // [32][256]       16 KB
  float* Lw = (float*)(ws + 38043648);            // [8][4096]      128 KB

  cast_all_kernel<<<576, 256, 0, stream>>>(h1_w, h2_w, f_w, g_w, wWh);

  transpose_cast_kernel<<<dim3(64, 4, 8), 256, 0, stream>>>(x1, x2, xt);

  conv_fg_kernel<<<dim3(64, 8), 256, 0, stream>>>(wWf, f_b, wWg, g_b, xt, ftw, gtw);

  stats_kernel<<<dim3(128, 4, 2), 256, 0, stream>>>(ftw, gtw, Lw);

  conv_h_kernel<<<dim3(64, 4, 8), 256, 0, stream>>>(wWh, h1_b, h2_b, xt, Lw, wh);

  apply_kernel<<<dim3(64, 4, 2), 512, 0, stream>>>(ftw, gtw, wh, x1, x2,
                                                   gamma1, gamma2, out);
}

// Round 8
// 332.345 us; speedup vs baseline: 2.0667x; 2.0667x over previous
//
#include <hip/hip_runtime.h>
#include <hip/hip_bf16.h>
#include <math.h>

#define NDIM 4096
#define CDIM 256
#define KD   32
#define SCALE 0.17677669529663687f  // 1/sqrt(32)
#define SHIFT 8.0f

typedef __attribute__((ext_vector_type(8))) short short8;  // 8 bf16 = 4 VGPRs
typedef __attribute__((ext_vector_type(4))) float f32x4;
typedef unsigned short u16;
typedef unsigned int u32;

__device__ __forceinline__ u32 f2bf(float x) {  // fp32 -> bf16 bits, RNE
  union { float f; u32 u; } v; v.f = x;
  return (v.u + 0x7FFFu + ((v.u >> 16) & 1u)) >> 16;
}

__device__ __forceinline__ u32 pack_bf16x2(float a, float b) {
  __hip_bfloat162 h2 = __float22bfloat162_rn(make_float2(a, b));
  u32 r;
  __builtin_memcpy(&r, &h2, 4);
  return r;
}

#define MFMA16(a, b, c) __builtin_amdgcn_mfma_f32_16x16x32_bf16((a), (b), (c), 0, 0, 0)

// ---------------------------------------------------------------------------
// cast all weights fp32 -> bf16 into one contiguous ws region
// ---------------------------------------------------------------------------
__global__ void cast_all_kernel(const float* __restrict__ h1w,
                                const float* __restrict__ h2w,
                                const float* __restrict__ fw,
                                const float* __restrict__ gw,
                                u16* __restrict__ dst) {
  int i = blockIdx.x * 256 + threadIdx.x;
  float v;
  if (i < 65536) v = h1w[i];
  else if (i < 131072) v = h2w[i - 65536];
  else if (i < 139264) v = fw[i - 131072];
  else v = gw[i - 139264];
  dst[i] = (u16)f2bf(v);
}

// ---------------------------------------------------------------------------
// x[b][C][n] fp32 -> xT[bb][n][C] bf16
// ---------------------------------------------------------------------------
__global__ __launch_bounds__(256) void transpose_cast_kernel(
    const float* __restrict__ x1, const float* __restrict__ x2,
    u16* __restrict__ xt) {
  __shared__ float ts[64][68];
  const int t = threadIdx.x;
  const int ntile = blockIdx.x * 64, Ctile = blockIdx.y * 64, z = blockIdx.z;
  const float* xb = ((z >> 2) ? x2 : x1) + (size_t)(z & 3) * CDIM * NDIM;
  u16* xtb = xt + (size_t)z * NDIM * CDIM;
  const int r = t >> 4, c4 = (t & 15) * 4;
#pragma unroll
  for (int i = 0; i < 4; i++) {
    float4 v = *(const float4*)&xb[(size_t)(Ctile + r + i * 16) * NDIM + ntile + c4];
    *(float4*)&ts[r + i * 16][c4] = v;
  }
  __syncthreads();
  const int n = t >> 2, Cg = (t & 3) * 16;
  u32 pk[8];
#pragma unroll
  for (int j = 0; j < 8; j++) {
    u32 lo = f2bf(ts[Cg + 2 * j][n]);
    u32 hi = f2bf(ts[Cg + 2 * j + 1][n]);
    pk[j] = lo | (hi << 16);
  }
  uint4* dst = (uint4*)&xtb[(size_t)(ntile + n) * CDIM + Ctile + Cg];
  dst[0] = make_uint4(pk[0], pk[1], pk[2], pk[3]);
  dst[1] = make_uint4(pk[4], pk[5], pk[6], pk[7]);
}

// ---------------------------------------------------------------------------
// conv f+g fused via MFMA. block 256 (4 waves), tile 32o x 64n, grid (64, 8)
// ---------------------------------------------------------------------------
__global__ __launch_bounds__(256) void conv_fg_kernel(
    const u16* __restrict__ Wf, const float* __restrict__ fbias,
    const u16* __restrict__ Wg, const float* __restrict__ gbias,
    const u16* __restrict__ xt, u16* __restrict__ ftT, u16* __restrict__ gtT) {
  const int t = threadIdx.x, w = t >> 6, l = t & 63, li = l & 15, q = l >> 4;
  const int ntile = blockIdx.x * 64, bb = blockIdx.y;
  const u16* xtb = xt + (size_t)bb * NDIM * CDIM;
  f32x4 zero4 = {0.f, 0.f, 0.f, 0.f};
  f32x4 acc[2][2];
  for (int i = 0; i < 2; i++) for (int j = 0; j < 2; j++) acc[i][j] = zero4;
  const int nrow = ntile + w * 16 + li;

  for (int k0 = 0; k0 < CDIM; k0 += 32) {
    short8 bx = *(const short8*)&xtb[(size_t)nrow * CDIM + k0 + q * 8];
    short8 af0 = *(const short8*)&Wf[(size_t)(li) * CDIM + k0 + q * 8];
    short8 af1 = *(const short8*)&Wf[(size_t)(16 + li) * CDIM + k0 + q * 8];
    short8 ag0 = *(const short8*)&Wg[(size_t)(li) * CDIM + k0 + q * 8];
    short8 ag1 = *(const short8*)&Wg[(size_t)(16 + li) * CDIM + k0 + q * 8];
    acc[0][0] = MFMA16(af0, bx, acc[0][0]);
    acc[0][1] = MFMA16(af1, bx, acc[0][1]);
    acc[1][0] = MFMA16(ag0, bx, acc[1][0]);
    acc[1][1] = MFMA16(ag1, bx, acc[1][1]);
  }
  u16* outs[2] = {ftT + (size_t)bb * NDIM * KD, gtT + (size_t)bb * NDIM * KD};
  const float* biases[2] = {fbias, gbias};
#pragma unroll
  for (int fg = 0; fg < 2; fg++) {
#pragma unroll
    for (int os = 0; os < 2; os++) {
      float b0 = biases[fg][os * 16 + q * 4 + 0];
      float b1 = biases[fg][os * 16 + q * 4 + 1];
      float b2 = biases[fg][os * 16 + q * 4 + 2];
      float b3 = biases[fg][os * 16 + q * 4 + 3];
      u32 p0 = f2bf(acc[fg][os][0] + b0) | (f2bf(acc[fg][os][1] + b1) << 16);
      u32 p1 = f2bf(acc[fg][os][2] + b2) | (f2bf(acc[fg][os][3] + b3) << 16);
      *(uint2*)&outs[fg][(size_t)nrow * KD + os * 16 + q * 4] = make_uint2(p0, p1);
    }
  }
}

// ---------------------------------------------------------------------------
// stats: L[n] = SHIFT + log(sum_m exp(s[n,m]-SHIFT))
// ---------------------------------------------------------------------------
__global__ __launch_bounds__(256) void stats_kernel(
    const u16* __restrict__ ft, const u16* __restrict__ gt,
    float* __restrict__ L) {
  __shared__ float zred[32][64];
  const int t = threadIdx.x, w = t >> 6, l = t & 63, li = l & 15, q = l >> 4;
  const int n0 = blockIdx.x * 32;
  const int bb = blockIdx.z * 4 + blockIdx.y;
  const u16* ftb = ft + (size_t)bb * NDIM * KD;
  const u16* gtb = gt + (size_t)bb * NDIM * KD;
  f32x4 zero4 = {0.f, 0.f, 0.f, 0.f};

  short8 a0 = *(const short8*)&ftb[(size_t)(n0 + li) * KD + q * 8];
  short8 a1 = *(const short8*)&ftb[(size_t)(n0 + 16 + li) * KD + q * 8];
  f32x4 z0 = zero4, z1 = zero4;

#pragma unroll 2
  for (int it = 0; it < 64; it++) {
    int m = (it * 4 + w) * 16;
    short8 bf = *(const short8*)&gtb[(size_t)(m + li) * KD + q * 8];
    f32x4 S0 = MFMA16(a0, bf, zero4);
    f32x4 S1 = MFMA16(a1, bf, zero4);
#pragma unroll
    for (int reg = 0; reg < 4; reg++) {
      z0[reg] += __expf(S0[reg] * SCALE - SHIFT);
      z1[reg] += __expf(S1[reg] * SCALE - SHIFT);
    }
  }
#pragma unroll
  for (int reg = 0; reg < 4; reg++) {
    zred[q * 4 + reg][w * 16 + li] = z0[reg];
    zred[16 + q * 4 + reg][w * 16 + li] = z1[reg];
  }
  __syncthreads();
  const int r = t >> 3, i8 = t & 7;
  float4 s1 = *(const float4*)&zred[r][i8 * 8];
  float4 s2 = *(const float4*)&zred[r][i8 * 8 + 4];
  float sum = s1.x + s1.y + s1.z + s1.w + s2.x + s2.y + s2.z + s2.w;
  sum += __shfl_xor(sum, 1, 8);
  sum += __shfl_xor(sum, 2, 8);
  sum += __shfl_xor(sum, 4, 8);
  if (i8 == 0) L[(size_t)bb * NDIM + n0 + r] = SHIFT + __logf(sum);
}

// ---------------------------------------------------------------------------
// conv h (both branches) via MFMA, with e^{-L[n]} folded into the output:
// h'[c][n] = (W @ x + bias)[c][n] * exp(-L[n]).
// ---------------------------------------------------------------------------
__global__ __launch_bounds__(256) void conv_h_kernel(
    const u16* __restrict__ Wall, const float* __restrict__ b1,
    const float* __restrict__ b2, const u16* __restrict__ xt,
    const float* __restrict__ L, u16* __restrict__ outH) {
  const int t = threadIdx.x, w = t >> 6, l = t & 63, li = l & 15, q = l >> 4;
  const int ntile = blockIdx.x * 64;
  const int o0 = blockIdx.y * 64 + w * 16;
  const int bb = blockIdx.z, branch = bb >> 2;
  const u16* W = Wall + (size_t)branch * CDIM * CDIM;
  const float* bias = branch ? b2 : b1;
  const u16* xtb = xt + (size_t)bb * NDIM * CDIM;
  const float* Lb = L + (size_t)bb * NDIM;
  u16* ob = outH + (size_t)bb * CDIM * NDIM;
  f32x4 zero4 = {0.f, 0.f, 0.f, 0.f};
  f32x4 acc[4];
  for (int i = 0; i < 4; i++) acc[i] = zero4;

  for (int k0 = 0; k0 < CDIM; k0 += 32) {
    short8 a = *(const short8*)&W[(size_t)(o0 + li) * CDIM + k0 + q * 8];
#pragma unroll
    for (int ns = 0; ns < 4; ns++) {
      short8 bf = *(const short8*)&xtb[(size_t)(ntile + ns * 16 + li) * CDIM + k0 + q * 8];
      acc[ns] = MFMA16(a, bf, acc[ns]);
    }
  }
  float bv[4];
#pragma unroll
  for (int reg = 0; reg < 4; reg++) bv[reg] = bias[o0 + q * 4 + reg];
#pragma unroll
  for (int ns = 0; ns < 4; ns++) {
    int n = ntile + ns * 16 + li;
    float ex = __expf(-Lb[n]);
#pragma unroll
    for (int reg = 0; reg < 4; reg++) {
      int c = o0 + q * 4 + reg;
      ob[(size_t)c * NDIM + n] = (u16)f2bf((acc[ns][reg] + bv[reg]) * ex);
    }
  }
}

// ---------------------------------------------------------------------------
// apply v8: out[c][m] = gamma * sum_n h'[c,n]*exp(s[n,m]*SCALE) + x[c][m]
// Block 1024 (16 waves), m-tile 128, C=256, n-chunk 64, dbuf Pt, one barrier
// per chunk. grid (32, 4, 2) = 256 blocks = 1/CU.
// Score role: msub=w>>1 (8 m-subtiles), npair=w&1 (2 n-pairs) -> 32 tiles.
// PV role:    c0=(w&7)*32 (8 c-ranges), mgrp=(w>>3)*64 (2 m-halves);
//             16 PV MFMAs/wave. Same per-wave MFMA count as v4 but: total h
//             L2 traffic HALVED (256 blocks x 2MB vs 512 x 2MB) and one
//             barrier domain per CU per chunk instead of two.
// ---------------------------------------------------------------------------
__global__ __launch_bounds__(1024, 4) void apply_kernel(
    const u16* __restrict__ ft, const u16* __restrict__ gt,
    const u16* __restrict__ h,
    const float* __restrict__ x1, const float* __restrict__ x2,
    const float* __restrict__ gamma1, const float* __restrict__ gamma2,
    float* __restrict__ out) {
  __shared__ u16 Pt[2][128][72];  // [buf][m][n64], 72 u16 row = 9 groups (odd)
  const int t = threadIdx.x, w = t >> 6, l = t & 63, li = l & 15, q = l >> 4;
  const int mtile = blockIdx.x * 128;
  const int b = blockIdx.y, br = blockIdx.z, bb = br * 4 + b;
  const u16* ftb = ft + (size_t)bb * NDIM * KD;
  const u16* gtb = gt + (size_t)bb * NDIM * KD;
  const u16* hb = h + (size_t)bb * CDIM * NDIM;
  const float* xb = (br ? x2 : x1) + (size_t)b * CDIM * NDIM;
  const float gmv = br ? gamma2[0] : gamma1[0];
  float* ob = out + (size_t)bb * CDIM * NDIM;

  const int msub_s = w >> 1, npair = w & 1;   // score role
  const int c0 = (w & 7) * 32;                // PV role: 32 channels
  const int mg = (w >> 3) * 64;               // PV role: m-half
  f32x4 zero4 = {0.f, 0.f, 0.f, 0.f};
  short8 gfrag = *(const short8*)&gtb[(size_t)(mtile + msub_s * 16 + li) * KD + q * 8];

  f32x4 acc[2][4];
  for (int i = 0; i < 2; i++) for (int j = 0; j < 4; j++) acc[i][j] = zero4;

  // prologue: P(0), prefetch f for chunk 1
  u32 Ppk[2][2];
  short8 afA[2];
#pragma unroll
  for (int j = 0; j < 2; j++) {
    int n = (npair * 2 + j) * 16;
    short8 a = *(const short8*)&ftb[(size_t)(n + li) * KD + q * 8];
    f32x4 S = MFMA16(a, gfrag, zero4);
    Ppk[j][0] = pack_bf16x2(__expf(S[0] * SCALE), __expf(S[1] * SCALE));
    Ppk[j][1] = pack_bf16x2(__expf(S[2] * SCALE), __expf(S[3] * SCALE));
  }
#pragma unroll
  for (int j = 0; j < 2; j++)
    afA[j] = *(const short8*)&ftb[(size_t)(64 + (npair * 2 + j) * 16 + li) * KD + q * 8];

  for (int i = 0; i < 64; i++) {
    const int n0 = i * 64;
    const int buf = i & 1;
    // h loads for this chunk (latency hides behind score+exp)
    short8 ah[2][2];
#pragma unroll
    for (int cs = 0; cs < 2; cs++)
#pragma unroll
      for (int kh = 0; kh < 2; kh++)
        ah[cs][kh] = *(const short8*)
            &hb[(size_t)(c0 + cs * 16 + li) * NDIM + n0 + kh * 32 + q * 8];

    // publish P_i (computed last iteration)
#pragma unroll
    for (int j = 0; j < 2; j++)
      *(uint2*)&Pt[buf][msub_s * 16 + li][(npair * 2 + j) * 16 + q * 4] =
          make_uint2(Ppk[j][0], Ppk[j][1]);

    // score+exp for chunk i+1
#pragma unroll
    for (int j = 0; j < 2; j++) {
      f32x4 S = MFMA16(afA[j], gfrag, zero4);
      Ppk[j][0] = pack_bf16x2(__expf(S[0] * SCALE), __expf(S[1] * SCALE));
      Ppk[j][1] = pack_bf16x2(__expf(S[2] * SCALE), __expf(S[3] * SCALE));
    }

    __syncthreads();  // single barrier: P_i visible, prior-buf reads done

    // prefetch f for chunk i+2
    {
      int ch2 = (i + 2 < 64) ? i + 2 : 63;
#pragma unroll
      for (int j = 0; j < 2; j++) {
        int n = ch2 * 64 + (npair * 2 + j) * 16;
        afA[j] = *(const short8*)&ftb[(size_t)(n + li) * KD + q * 8];
      }
    }

    // PV: 16 MFMAs against Pt[buf]
#pragma unroll
    for (int kh = 0; kh < 2; kh++) {
#pragma unroll
      for (int ms = 0; ms < 4; ms++) {
        short8 bm = *(const short8*)&Pt[buf][mg + ms * 16 + li][kh * 32 + q * 8];
        acc[0][ms] = MFMA16(ah[0][kh], bm, acc[0][ms]);
        acc[1][ms] = MFMA16(ah[1][kh], bm, acc[1][ms]);
      }
    }
  }

  // epilogue: out = gamma * acc + x
#pragma unroll
  for (int cs = 0; cs < 2; cs++) {
#pragma unroll
    for (int ms = 0; ms < 4; ms++) {
#pragma unroll
      for (int reg = 0; reg < 4; reg++) {
        int c = c0 + cs * 16 + q * 4 + reg;
        int m = mtile + mg + ms * 16 + li;
        size_t idx = (size_t)c * NDIM + m;
        ob[idx] = gmv * acc[cs][ms][reg] + xb[idx];
      }
    }
  }
}

// ---------------------------------------------------------------------------
extern "C" void kernel_launch(void* const* d_in, const int* in_sizes, int n_in,
                              void* d_out, int out_size, void* d_ws, size_t ws_size,
                              hipStream_t stream) {
  const float* x1 = (const float*)d_in[0];
  const float* x2 = (const float*)d_in[1];
  const float* f_w = (const float*)d_in[2];
  const float* f_b = (const float*)d_in[3];
  const float* g_w = (const float*)d_in[4];
  const float* g_b = (const float*)d_in[5];
  const float* h1_w = (const float*)d_in[6];
  const float* h1_b = (const float*)d_in[7];
  const float* h2_w = (const float*)d_in[8];
  const float* h2_b = (const float*)d_in[9];
  const float* gamma1 = (const float*)d_in[10];
  const float* gamma2 = (const float*)d_in[11];
  float* out = (float*)d_out;

  char* ws = (char*)d_ws;
  u16* xt  = (u16*)(ws);                          // [8][4096][256]  16 MB
  u16* wh  = (u16*)(ws + 16777216);               // [8][256][4096]  16 MB
  u16* ftw = (u16*)(ws + 33554432);               // [8][4096][32]    2 MB
  u16* gtw = (u16*)(ws + 35651584);               // [8][4096][32]    2 MB
  u16* wWh = (u16*)(ws + 37748736);               // [2][256][256]  256 KB
  u16* wWf = (u16*)(ws + 38010880);               // [32][256]       16 KB
  u16* wWg = (u16*)(ws + 38027264);               // [32][256]       16 KB
  float* Lw = (float*)(ws + 38043648);            // [8][4096]      128 KB

  cast_all_kernel<<<576, 256, 0, stream>>>(h1_w, h2_w, f_w, g_w, wWh);

  transpose_cast_kernel<<<dim3(64, 4, 8), 256, 0, stream>>>(x1, x2, xt);

  conv_fg_kernel<<<dim3(64, 8), 256, 0, stream>>>(wWf, f_b, wWg, g_b, xt, ftw, gtw);

  stats_kernel<<<dim3(128, 4, 2), 256, 0, stream>>>(ftw, gtw, Lw);

  conv_h_kernel<<<dim3(64, 4, 8), 256, 0, stream>>>(wWh, h1_b, h2_b, xt, Lw, wh);

  apply_kernel<<<dim3(32, 4, 2), 1024, 0, stream>>>(ftw, gtw, wh, x1, x2,
                                                    gamma1, gamma2, out);
}